// Round 7
// baseline (613.721 us; speedup 1.0000x reference)
//
#include <hip/hip_runtime.h>
#include <hip/hip_bf16.h>
#include <stdint.h>

#define NN 50000
#define NE 800000
#define NR 16
#define NP (NN * NR)                 // 800000 pair bins
#define NB1 ((NP + 255) / 256)       // 3125
#define NTILES ((NN + 127) / 128)    // 391

typedef unsigned short u16;
typedef unsigned int u32;

typedef __bf16 bf16x8 __attribute__((ext_vector_type(8)));
typedef __bf16 bf16x2 __attribute__((ext_vector_type(2)));
typedef float f32x4 __attribute__((ext_vector_type(4)));

__device__ __forceinline__ u16 f2bf(float f) {
  u32 u = __float_as_uint(f);
  u = u + 0x7FFFu + ((u >> 16) & 1u);
  return (u16)(u >> 16);
}

__device__ __forceinline__ u32 pk2bf(float x, float y) {
#if __has_builtin(__builtin_amdgcn_cvt_pk_bf16_f32)
  bf16x2 r = __builtin_amdgcn_cvt_pk_bf16_f32(x, y);
  union { bf16x2 v; u32 u; } c;
  c.v = r;
  return c.u;
#else
  return (u32)f2bf(x) | ((u32)f2bf(y) << 16);
#endif
}

__device__ __forceinline__ float bflo(u32 w) { return __uint_as_float(w << 16); }
__device__ __forceinline__ float bfhi(u32 w) { return __uint_as_float(w & 0xFFFF0000u); }

// ---------------- edge sort by (dst, rel) — counting sort over NP bins ----------------
__global__ void hist_kernel(const int* __restrict__ dst, const int* __restrict__ rel,
                            int* __restrict__ counts) {
  int e = blockIdx.x * 256 + threadIdx.x;
  if (e < NE) atomicAdd(&counts[dst[e] * NR + rel[e]], 1);
}

__global__ void scan_partial(const int* __restrict__ counts, int* __restrict__ bsum) {
  __shared__ int buf[256];
  int t = threadIdx.x;
  int i = blockIdx.x * 256 + t;
  int v = (i < NP) ? counts[i] : 0;
  buf[t] = v;
  __syncthreads();
  for (int off = 1; off < 256; off <<= 1) {
    int x = buf[t];
    int y = (t >= off) ? buf[t - off] : 0;
    __syncthreads();
    buf[t] = x + y;
    __syncthreads();
  }
  if (t == 255) bsum[blockIdx.x] = buf[255];
}

// single block, 1024 threads, 4-serial each: scans NB1 (<=4096) block sums
__global__ void scan_mid(const int* __restrict__ bsum, int* __restrict__ boff,
                         int* __restrict__ total_out) {
  __shared__ int buf[1024];
  int t = threadIdx.x;
  int v[4];
  int sum = 0;
#pragma unroll
  for (int i = 0; i < 4; ++i) {
    int idx = t * 4 + i;
    v[i] = (idx < NB1) ? bsum[idx] : 0;
    sum += v[i];
  }
  buf[t] = sum;
  __syncthreads();
  for (int off = 1; off < 1024; off <<= 1) {
    int x = buf[t];
    int y = (t >= off) ? buf[t - off] : 0;
    __syncthreads();
    buf[t] = x + y;
    __syncthreads();
  }
  int excl = buf[t] - sum;
#pragma unroll
  for (int i = 0; i < 4; ++i) {
    int idx = t * 4 + i;
    if (idx < NB1) { boff[idx] = excl; excl += v[i]; }
  }
  if (t == 1023) *total_out = buf[1023];
}

__global__ void scan_final(const int* __restrict__ counts, const int* __restrict__ boff,
                           int* __restrict__ starts, int* __restrict__ cursor) {
  __shared__ int buf[256];
  int t = threadIdx.x;
  int i = blockIdx.x * 256 + t;
  int v = (i < NP) ? counts[i] : 0;
  buf[t] = v;
  __syncthreads();
  for (int off = 1; off < 256; off <<= 1) {
    int x = buf[t];
    int y = (t >= off) ? buf[t - off] : 0;
    __syncthreads();
    buf[t] = x + y;
    __syncthreads();
  }
  int s = boff[blockIdx.x] + buf[t] - v;
  if (i < NP) {
    starts[i] = s;
    cursor[i] = s;
  }
}

// esd[pos] = { rel<<16 | src, norm_bits }
__global__ void scatter_kernel(const int* __restrict__ src, const int* __restrict__ dst,
                               const int* __restrict__ rel, const float* __restrict__ norm,
                               int* __restrict__ cursor, uint2* __restrict__ esd) {
  int e = blockIdx.x * 256 + threadIdx.x;
  if (e < NE) {
    int r = rel[e];
    int pos = atomicAdd(&cursor[dst[e] * NR + r], 1);
    esd[pos] = make_uint2(((u32)r << 16) | (u32)src[e], __float_as_uint(norm[e]));
  }
}

// ---------------- weight convert: Wt[mat][d][k] = bf16(W[mat][k][d]) ----------------
// mats 0..15 = w0 rels, 16 = lw0, 17..32 = w1 rels, 33 = lw1
__global__ void convert_wt(const float* __restrict__ w0, const float* __restrict__ lw0,
                           const float* __restrict__ w1, const float* __restrict__ lw1,
                           u16* __restrict__ Wt) {
  int m = blockIdx.y;
  int idx = blockIdx.x * 256 + threadIdx.x; // 0..16383
  int d = idx >> 7, k = idx & 127;
  const float* s;
  if (m < 16) s = w0 + (size_t)m * 16384;
  else if (m == 16) s = lw0;
  else if (m < 33) s = w1 + (size_t)(m - 17) * 16384;
  else s = lw1;
  Wt[(size_t)m * 16384 + idx] = f2bf(s[k * 128 + d]);
}

// ---------------- h f32 -> bf16 (layer 0 input only) ----------------
__global__ void hconv_kernel(const float* __restrict__ h, u16* __restrict__ hbf) {
  int i = blockIdx.x * 256 + threadIdx.x; // float4 index
  float4 v = ((const float4*)h)[i];
  ushort4 u;
  u.x = f2bf(v.x); u.y = f2bf(v.y); u.z = f2bf(v.z); u.w = f2bf(v.w);
  ((ushort4*)hbf)[i] = u;
}

// ---------------- gate table: gates[r][n] = sigmoid(hbf[n] . gw[r]) ----------------
__global__ void gates_kernel(const u16* __restrict__ hbf, const float* __restrict__ gw,
                             float* __restrict__ gates) {
  __shared__ float hs[16 * 132];
  __shared__ float gws[16 * 132];
  int t = threadIdx.x;
  int n0 = blockIdx.x * 16;
#pragma unroll
  for (int i = 0; i < 2; ++i) {
    int f = t + 256 * i;            // 0..511
    int row = f >> 5, c4 = (f & 31) * 4;
    ushort4 u = *(const ushort4*)&hbf[(size_t)(n0 + row) * 128 + c4];
    hs[row * 132 + c4 + 0] = __uint_as_float((u32)u.x << 16);
    hs[row * 132 + c4 + 1] = __uint_as_float((u32)u.y << 16);
    hs[row * 132 + c4 + 2] = __uint_as_float((u32)u.z << 16);
    hs[row * 132 + c4 + 3] = __uint_as_float((u32)u.w << 16);
    *(float4*)&gws[row * 132 + c4] = *(const float4*)&gw[row * 128 + c4];
  }
  __syncthreads();
  int nl = t >> 4, r = t & 15;
  float s = 0.f;
#pragma unroll 8
  for (int k = 0; k < 128; ++k) s += hs[nl * 132 + k] * gws[r * 132 + k];
  gates[r * NN + n0 + nl] = 1.f / (1.f + __expf(-s));
}

// ---------------- aggregate-first: agg[r][v][:] = sum coef * hbf[src] ----------------
// Edges sorted by (dst,rel) -> per wave (node), rel is nondecreasing: running flush.
// Chunk-8, FULLY UNROLLED (fixed trip count) so p[]/w[]/gt[] stay in registers.
__global__ __launch_bounds__(256)
void aggregate_kernel(const u32* __restrict__ hbf32, const uint2* __restrict__ esd,
                      const float* __restrict__ gates, const int* __restrict__ starts,
                      u32* __restrict__ agg) {
  int wave = threadIdx.x >> 6, lane = threadIdx.x & 63;
  int v = blockIdx.x * 4 + wave;
  if (v >= NN) return;
  int s = starts[v * NR];
  int e = starts[v * NR + NR];
  u32* aggp = agg + (size_t)v * 64 + lane;   // [r][v][d] layout: + r*NN*64 per flush
  float a0 = 0.f, a1 = 0.f;
  int cur = 0;
  int j = s;
  for (; j + 8 <= e; j += 8) {
    uint2 p[8];
#pragma unroll
    for (int i = 0; i < 8; ++i) p[i] = esd[j + i];
    u32 w[8];
    float gt[8];
#pragma unroll
    for (int i = 0; i < 8; ++i) {
      u32 rs = p[i].x;
      u32 sn = rs & 0xFFFFu;
      w[i] = hbf32[sn * 64u + (u32)lane];      // L2/L3-resident gather
      gt[i] = gates[(rs >> 16) * (u32)NN + sn];
    }
#pragma unroll
    for (int i = 0; i < 8; ++i) {
      int rel = (int)(p[i].x >> 16);
      while (cur < rel) {                       // wave-uniform flush walk
        aggp[(size_t)cur * NN * 64] = pk2bf(a0, a1);
        a0 = 0.f; a1 = 0.f;
        ++cur;
      }
      float coef = gt[i] * __uint_as_float(p[i].y);
      a0 = fmaf(coef, bflo(w[i]), a0);
      a1 = fmaf(coef, bfhi(w[i]), a1);
    }
  }
  for (; j < e; ++j) {
    uint2 p = esd[j];
    u32 rs = p.x;
    u32 sn = rs & 0xFFFFu;
    int rel = (int)(rs >> 16);
    while (cur < rel) {
      aggp[(size_t)cur * NN * 64] = pk2bf(a0, a1);
      a0 = 0.f; a1 = 0.f;
      ++cur;
    }
    float coef = gates[(u32)rel * (u32)NN + sn] * __uint_as_float(p.y);
    u32 w = hbf32[sn * 64u + (u32)lane];
    a0 = fmaf(coef, bflo(w), a0);
    a1 = fmaf(coef, bfhi(w), a1);
  }
  while (cur < NR) {
    aggp[(size_t)cur * NN * 64] = pk2bf(a0, a1);
    a0 = 0.f; a1 = 0.f;
    ++cur;
  }
}

// ---------------- fused GEMM: out[v] = sum_{r=0..15} agg_r[v] @ W_r + h[v] @ loop_w + b --
// 17 mats accumulated in persistent AGPRs. Register-prefetch pipeline: mat m+1's global
// loads are issued right after the staging barrier and consumed at the NEXT iteration's
// LDS write, so they stay in flight across the whole MFMA phase + both barriers
// (R6 counters: MFMA 13% / VALU 8% — staging and compute were serialized).
template <int LAYER>
__global__ __launch_bounds__(256, 2)
void biggemm_kernel(const u16* __restrict__ aggu, const u16* __restrict__ hbf,
                    const u16* __restrict__ Wt, const float* __restrict__ bias,
                    u16* __restrict__ hb_out, float* __restrict__ fout) {
  __shared__ u16 As[128 * 136]; // node-rows tile (agg_r or hbf), pad +8
  __shared__ u16 Ws[128 * 136]; // W rows = d
  int t = threadIdx.x;
  int n0 = blockIdx.x * 128;
  int wave = t >> 6, lane = t & 63;
  int wd = (wave & 1) * 64, wn = (wave >> 1) * 64;
  int mrow = lane & 15, quad = lane >> 4;
  float4 bv[4];
#pragma unroll
  for (int i = 0; i < 4; ++i) bv[i] = *(const float4*)&bias[wd + i * 16 + quad * 4];
  f32x4 acc[4][4];
#pragma unroll
  for (int i = 0; i < 4; ++i)
#pragma unroll
    for (int j = 0; j < 4; ++j) acc[i][j] = (f32x4){0.f, 0.f, 0.f, 0.f};

  uint4 ra[8], rw[8];
  auto issue = [&](int m) {
#pragma unroll
    for (int i = 0; i < 8; ++i) {
      int u8 = t + 256 * i;          // uint4 index, 0..2047
      int row = u8 >> 4, c8 = (u8 & 15) * 8;
      int n = n0 + row;
      rw[i] = *(const uint4*)&Wt[(size_t)m * 16384 + row * 128 + c8];
      uint4 v = make_uint4(0, 0, 0, 0);
      if (n < NN) {
        const u16* srcrow = (m < 16) ? aggu + ((size_t)m * NN + n) * 128
                                     : hbf + (size_t)n * 128;
        v = *(const uint4*)&srcrow[c8];
      }
      ra[i] = v;
    }
  };
  issue(0);
  for (int m = 0; m < 17; ++m) {
    // commit prefetched regs to LDS (s_waitcnt vmcnt happens here, after a full
    // MFMA phase of latency hiding)
#pragma unroll
    for (int i = 0; i < 8; ++i) {
      int u8 = t + 256 * i;
      int row = u8 >> 4, c8 = (u8 & 15) * 8;
      *(uint4*)&As[row * 136 + c8] = ra[i];
      *(uint4*)&Ws[row * 136 + c8] = rw[i];
    }
    __syncthreads();
    if (m < 16) issue(m + 1);       // fire next mat's loads; no wait until next commit
#pragma unroll
    for (int kk = 0; kk < 4; ++kk) {
      int k0 = kk * 32 + quad * 8;
      bf16x8 a[4], b[4];
#pragma unroll
      for (int i = 0; i < 4; ++i) a[i] = *(const bf16x8*)&Ws[(wd + i * 16 + mrow) * 136 + k0];
#pragma unroll
      for (int j = 0; j < 4; ++j) b[j] = *(const bf16x8*)&As[(wn + j * 16 + mrow) * 136 + k0];
#pragma unroll
      for (int i = 0; i < 4; ++i)
#pragma unroll
        for (int j = 0; j < 4; ++j)
          acc[i][j] = __builtin_amdgcn_mfma_f32_16x16x32_bf16(a[i], b[j], acc[i][j], 0, 0, 0);
    }
    __syncthreads();               // all waves done reading LDS before next commit
  }
  // epilogue: lane owns node = n0+wn+j*16+mrow, d = wd+i*16+quad*4 .. +3 (contiguous)
#pragma unroll
  for (int j = 0; j < 4; ++j) {
    int n = n0 + wn + j * 16 + mrow;
    if (n < NN) {
#pragma unroll
      for (int i = 0; i < 4; ++i) {
        int d0 = wd + i * 16 + quad * 4;
        float v0 = acc[i][j][0] + bv[i].x;
        float v1 = acc[i][j][1] + bv[i].y;
        float v2 = acc[i][j][2] + bv[i].z;
        float v3 = acc[i][j][3] + bv[i].w;
        if (LAYER == 0) {
          v0 = fmaxf(v0, 0.f); v1 = fmaxf(v1, 0.f);
          v2 = fmaxf(v2, 0.f); v3 = fmaxf(v3, 0.f);
          uint2 st;
          st.x = pk2bf(v0, v1);
          st.y = pk2bf(v2, v3);
          *(uint2*)&hb_out[(size_t)n * 128 + d0] = st;
        } else {
          float4 st = make_float4(v0, v1, v2, v3);
          *(float4*)&fout[(size_t)n * 128 + d0] = st;
        }
      }
    }
  }
}

// ---------------- host ----------------
extern "C" void kernel_launch(void* const* d_in, const int* in_sizes, int n_in,
                              void* d_out, int out_size, void* d_ws, size_t ws_size,
                              hipStream_t stream) {
  const float* h0   = (const float*)d_in[0];
  const float* norm = (const float*)d_in[1];
  const float* w0   = (const float*)d_in[2];
  const float* b0   = (const float*)d_in[3];
  const float* lw0  = (const float*)d_in[4];
  const float* gw0  = (const float*)d_in[5];
  const float* w1   = (const float*)d_in[6];
  const float* b1   = (const float*)d_in[7];
  const float* lw1  = (const float*)d_in[8];
  const float* gw1  = (const float*)d_in[9];
  const int*   src  = (const int*)d_in[10];
  const int*   dst  = (const int*)d_in[11];
  const int*   rel  = (const int*)d_in[12];
  float* out = (float*)d_out;

  char* p = (char*)d_ws;
  auto alloc = [&](size_t bytes) -> void* {
    void* q = (void*)p;
    p += (bytes + 255) & ~(size_t)255;
    return q;
  };
  u16*   Wt     = (u16*)alloc((size_t)34 * 16384 * 2);
  float* gates  = (float*)alloc((size_t)NR * NN * 4);
  u16*   hbf0   = (u16*)alloc((size_t)NN * 128 * 2);
  u16*   hbf1   = (u16*)alloc((size_t)NN * 128 * 2);
  int*   counts = (int*)alloc((size_t)NP * 4);
  int*   cursor = (int*)alloc((size_t)NP * 4);
  int*   starts = (int*)alloc((size_t)(NP + 1) * 4);
  int*   bsum   = (int*)alloc((size_t)NB1 * 4);
  int*   boff   = (int*)alloc((size_t)NB1 * 4);
  uint2* esd    = (uint2*)alloc((size_t)NE * 8);
  u32*   agg    = (u32*)alloc((size_t)NN * NR * 64 * 4); // [r][v][128] bf16 = 204.8 MB

  // ---- sort edges by (dst, rel) — shared by both layers ----
  hipMemsetAsync(counts, 0, (size_t)NP * 4, stream);
  hist_kernel<<<NE / 256, 256, 0, stream>>>(dst, rel, counts);
  scan_partial<<<NB1, 256, 0, stream>>>(counts, bsum);
  scan_mid<<<1, 1024, 0, stream>>>(bsum, boff, starts + NP);
  scan_final<<<NB1, 256, 0, stream>>>(counts, boff, starts, cursor);
  scatter_kernel<<<NE / 256, 256, 0, stream>>>(src, dst, rel, norm, cursor, esd);
  convert_wt<<<dim3(64, 34), 256, 0, stream>>>(w0, lw0, w1, lw1, Wt);
  hconv_kernel<<<NN * 32 / 256, 256, 0, stream>>>(h0, hbf0);

  // ---- layer 0 (relu, bf16 output) ----
  gates_kernel<<<NN / 16, 256, 0, stream>>>(hbf0, gw0, gates);
  aggregate_kernel<<<(NN + 3) / 4, 256, 0, stream>>>(
      (const u32*)hbf0, esd, gates, starts, agg);
  biggemm_kernel<0><<<NTILES, 256, 0, stream>>>(
      (const u16*)agg, hbf0, Wt, b0, hbf1, nullptr);

  // ---- layer 1 (no relu, f32 output) ----
  gates_kernel<<<NN / 16, 256, 0, stream>>>(hbf1, gw1, gates);
  aggregate_kernel<<<(NN + 3) / 4, 256, 0, stream>>>(
      (const u32*)hbf1, esd, gates, starts, agg);
  biggemm_kernel<1><<<NTILES, 256, 0, stream>>>(
      (const u16*)agg, hbf1, Wt + (size_t)17 * 16384, b1, nullptr, out);
}

// Round 8
// 451.168 us; speedup vs baseline: 1.3603x; 1.3603x over previous
//
#include <hip/hip_runtime.h>
#include <hip/hip_bf16.h>
#include <stdint.h>

#define NN 50000
#define NE 800000
#define NR 16
#define NP (NN * NR)                 // 800000 pair bins
#define NB1 ((NP + 255) / 256)       // 3125
#define NTILES ((NN + 127) / 128)    // 391

typedef unsigned short u16;
typedef unsigned int u32;

typedef __bf16 bf16x8 __attribute__((ext_vector_type(8)));
typedef __bf16 bf16x2 __attribute__((ext_vector_type(2)));
typedef float f32x4 __attribute__((ext_vector_type(4)));

__device__ __forceinline__ u16 f2bf(float f) {
  u32 u = __float_as_uint(f);
  u = u + 0x7FFFu + ((u >> 16) & 1u);
  return (u16)(u >> 16);
}

__device__ __forceinline__ u32 pk2bf(float x, float y) {
#if __has_builtin(__builtin_amdgcn_cvt_pk_bf16_f32)
  bf16x2 r = __builtin_amdgcn_cvt_pk_bf16_f32(x, y);
  union { bf16x2 v; u32 u; } c;
  c.v = r;
  return c.u;
#else
  return (u32)f2bf(x) | ((u32)f2bf(y) << 16);
#endif
}

__device__ __forceinline__ float bflo(u32 w) { return __uint_as_float(w << 16); }
__device__ __forceinline__ float bfhi(u32 w) { return __uint_as_float(w & 0xFFFF0000u); }

// ---------------- edge sort by (dst, rel) — counting sort over NP bins ----------------
__global__ void hist_kernel(const int* __restrict__ dst, const int* __restrict__ rel,
                            int* __restrict__ counts) {
  int e = blockIdx.x * 256 + threadIdx.x;
  if (e < NE) atomicAdd(&counts[dst[e] * NR + rel[e]], 1);
}

__global__ void scan_partial(const int* __restrict__ counts, int* __restrict__ bsum) {
  __shared__ int buf[256];
  int t = threadIdx.x;
  int i = blockIdx.x * 256 + t;
  int v = (i < NP) ? counts[i] : 0;
  buf[t] = v;
  __syncthreads();
  for (int off = 1; off < 256; off <<= 1) {
    int x = buf[t];
    int y = (t >= off) ? buf[t - off] : 0;
    __syncthreads();
    buf[t] = x + y;
    __syncthreads();
  }
  if (t == 255) bsum[blockIdx.x] = buf[255];
}

// single block, 1024 threads, 4-serial each: scans NB1 (<=4096) block sums
__global__ void scan_mid(const int* __restrict__ bsum, int* __restrict__ boff,
                         int* __restrict__ total_out) {
  __shared__ int buf[1024];
  int t = threadIdx.x;
  int v[4];
  int sum = 0;
#pragma unroll
  for (int i = 0; i < 4; ++i) {
    int idx = t * 4 + i;
    v[i] = (idx < NB1) ? bsum[idx] : 0;
    sum += v[i];
  }
  buf[t] = sum;
  __syncthreads();
  for (int off = 1; off < 1024; off <<= 1) {
    int x = buf[t];
    int y = (t >= off) ? buf[t - off] : 0;
    __syncthreads();
    buf[t] = x + y;
    __syncthreads();
  }
  int excl = buf[t] - sum;
#pragma unroll
  for (int i = 0; i < 4; ++i) {
    int idx = t * 4 + i;
    if (idx < NB1) { boff[idx] = excl; excl += v[i]; }
  }
  if (t == 1023) *total_out = buf[1023];
}

__global__ void scan_final(const int* __restrict__ counts, const int* __restrict__ boff,
                           int* __restrict__ starts, int* __restrict__ cursor) {
  __shared__ int buf[256];
  int t = threadIdx.x;
  int i = blockIdx.x * 256 + t;
  int v = (i < NP) ? counts[i] : 0;
  buf[t] = v;
  __syncthreads();
  for (int off = 1; off < 256; off <<= 1) {
    int x = buf[t];
    int y = (t >= off) ? buf[t - off] : 0;
    __syncthreads();
    buf[t] = x + y;
    __syncthreads();
  }
  int s = boff[blockIdx.x] + buf[t] - v;
  if (i < NP) {
    starts[i] = s;
    cursor[i] = s;
  }
}

// esd[pos] = { rel<<16 | src, norm_bits }
__global__ void scatter_kernel(const int* __restrict__ src, const int* __restrict__ dst,
                               const int* __restrict__ rel, const float* __restrict__ norm,
                               int* __restrict__ cursor, uint2* __restrict__ esd) {
  int e = blockIdx.x * 256 + threadIdx.x;
  if (e < NE) {
    int r = rel[e];
    int pos = atomicAdd(&cursor[dst[e] * NR + r], 1);
    esd[pos] = make_uint2(((u32)r << 16) | (u32)src[e], __float_as_uint(norm[e]));
  }
}

// ---------------- weight convert: Wt[mat][d][k] = bf16(W[mat][k][d]) ----------------
// mats 0..15 = w0 rels, 16 = lw0, 17..32 = w1 rels, 33 = lw1
__global__ void convert_wt(const float* __restrict__ w0, const float* __restrict__ lw0,
                           const float* __restrict__ w1, const float* __restrict__ lw1,
                           u16* __restrict__ Wt) {
  int m = blockIdx.y;
  int idx = blockIdx.x * 256 + threadIdx.x; // 0..16383
  int d = idx >> 7, k = idx & 127;
  const float* s;
  if (m < 16) s = w0 + (size_t)m * 16384;
  else if (m == 16) s = lw0;
  else if (m < 33) s = w1 + (size_t)(m - 17) * 16384;
  else s = lw1;
  Wt[(size_t)m * 16384 + idx] = f2bf(s[k * 128 + d]);
}

// ---------------- h f32 -> bf16 (layer 0 input only) ----------------
__global__ void hconv_kernel(const float* __restrict__ h, u16* __restrict__ hbf) {
  int i = blockIdx.x * 256 + threadIdx.x; // float4 index
  float4 v = ((const float4*)h)[i];
  ushort4 u;
  u.x = f2bf(v.x); u.y = f2bf(v.y); u.z = f2bf(v.z); u.w = f2bf(v.w);
  ((ushort4*)hbf)[i] = u;
}

// ---------------- gate table: gates[r][n] = sigmoid(hbf[n] . gw[r]) ----------------
__global__ void gates_kernel(const u16* __restrict__ hbf, const float* __restrict__ gw,
                             float* __restrict__ gates) {
  __shared__ float hs[16 * 132];
  __shared__ float gws[16 * 132];
  int t = threadIdx.x;
  int n0 = blockIdx.x * 16;
#pragma unroll
  for (int i = 0; i < 2; ++i) {
    int f = t + 256 * i;            // 0..511
    int row = f >> 5, c4 = (f & 31) * 4;
    ushort4 u = *(const ushort4*)&hbf[(size_t)(n0 + row) * 128 + c4];
    hs[row * 132 + c4 + 0] = __uint_as_float((u32)u.x << 16);
    hs[row * 132 + c4 + 1] = __uint_as_float((u32)u.y << 16);
    hs[row * 132 + c4 + 2] = __uint_as_float((u32)u.z << 16);
    hs[row * 132 + c4 + 3] = __uint_as_float((u32)u.w << 16);
    *(float4*)&gws[row * 132 + c4] = *(const float4*)&gw[row * 128 + c4];
  }
  __syncthreads();
  int nl = t >> 4, r = t & 15;
  float s = 0.f;
#pragma unroll 8
  for (int k = 0; k < 128; ++k) s += hs[nl * 132 + k] * gws[r * 132 + k];
  gates[r * NN + n0 + nl] = 1.f / (1.f + __expf(-s));
}

// ---------------- aggregate-first: agg[r][v][:] = sum coef * hbf[src] ----------------
// Edges sorted by (dst,rel) -> per wave (node), rel is nondecreasing: running flush.
// Chunk-8, FULLY UNROLLED (fixed trip count) so p[]/w[]/gt[] stay in registers.
__global__ __launch_bounds__(256)
void aggregate_kernel(const u32* __restrict__ hbf32, const uint2* __restrict__ esd,
                      const float* __restrict__ gates, const int* __restrict__ starts,
                      u32* __restrict__ agg) {
  int wave = threadIdx.x >> 6, lane = threadIdx.x & 63;
  int v = blockIdx.x * 4 + wave;
  if (v >= NN) return;
  int s = starts[v * NR];
  int e = starts[v * NR + NR];
  u32* aggp = agg + (size_t)v * 64 + lane;   // [r][v][d] layout: + r*NN*64 per flush
  float a0 = 0.f, a1 = 0.f;
  int cur = 0;
  int j = s;
  for (; j + 8 <= e; j += 8) {
    uint2 p[8];
#pragma unroll
    for (int i = 0; i < 8; ++i) p[i] = esd[j + i];
    u32 w[8];
    float gt[8];
#pragma unroll
    for (int i = 0; i < 8; ++i) {
      u32 rs = p[i].x;
      u32 sn = rs & 0xFFFFu;
      w[i] = hbf32[sn * 64u + (u32)lane];      // L2/L3-resident gather
      gt[i] = gates[(rs >> 16) * (u32)NN + sn];
    }
#pragma unroll
    for (int i = 0; i < 8; ++i) {
      int rel = (int)(p[i].x >> 16);
      while (cur < rel) {                       // wave-uniform flush walk
        aggp[(size_t)cur * NN * 64] = pk2bf(a0, a1);
        a0 = 0.f; a1 = 0.f;
        ++cur;
      }
      float coef = gt[i] * __uint_as_float(p[i].y);
      a0 = fmaf(coef, bflo(w[i]), a0);
      a1 = fmaf(coef, bfhi(w[i]), a1);
    }
  }
  for (; j < e; ++j) {
    uint2 p = esd[j];
    u32 rs = p.x;
    u32 sn = rs & 0xFFFFu;
    int rel = (int)(rs >> 16);
    while (cur < rel) {
      aggp[(size_t)cur * NN * 64] = pk2bf(a0, a1);
      a0 = 0.f; a1 = 0.f;
      ++cur;
    }
    float coef = gates[(u32)rel * (u32)NN + sn] * __uint_as_float(p.y);
    u32 w = hbf32[sn * 64u + (u32)lane];
    a0 = fmaf(coef, bflo(w), a0);
    a1 = fmaf(coef, bfhi(w), a1);
  }
  while (cur < NR) {
    aggp[(size_t)cur * NN * 64] = pk2bf(a0, a1);
    a0 = 0.f; a1 = 0.f;
    ++cur;
  }
}

// ---------------- fused GEMM: out[v] = sum_{r=0..15} agg_r[v] @ W_r + h[v] @ loop_w + b --
// 17 mats accumulated in persistent AGPRs. Register-prefetch pipeline, spill-proofed:
//  - 16 INDIVIDUALLY NAMED uint4 regs (macro-expanded), no arrays -> SROA can't fail
//  - last iteration peeled -> no conditional issue inside the loop
//  - OOB node rows handled by CLAMP (garbage only reaches output rows >= NN, never
//    stored) -> no per-lane cndmask/zero-fill
// (R7's array+lambda+guard version spilled to scratch: WRITE_SIZE 25->171 MB.)

#define REP8(X) X(0) X(1) X(2) X(3) X(4) X(5) X(6) X(7)

#define BG_ISSUE(i)                                                           \
  {                                                                           \
    int u8 = t + 256 * i;                                                     \
    int row = u8 >> 4, c8 = (u8 & 15) * 8;                                    \
    int n = n0 + row;                                                         \
    int nc = n < NN ? n : NN - 1;                                             \
    rw##i = *(const uint4*)&wbase[row * 128 + c8];                            \
    ra##i = *(const uint4*)&srcbase[(size_t)nc * 128 + c8];                   \
  }

#define BG_COMMIT(i)                                                          \
  {                                                                           \
    int u8 = t + 256 * i;                                                     \
    int row = u8 >> 4, c8 = (u8 & 15) * 8;                                    \
    *(uint4*)&As[row * 136 + c8] = ra##i;                                     \
    *(uint4*)&Ws[row * 136 + c8] = rw##i;                                     \
  }

#define BG_MFMA                                                               \
  _Pragma("unroll")                                                           \
  for (int kk = 0; kk < 4; ++kk) {                                            \
    int k0 = kk * 32 + quad * 8;                                              \
    bf16x8 fa[4], fb[4];                                                      \
    _Pragma("unroll")                                                         \
    for (int i2 = 0; i2 < 4; ++i2)                                            \
      fa[i2] = *(const bf16x8*)&Ws[(wd + i2 * 16 + mrow) * 136 + k0];         \
    _Pragma("unroll")                                                         \
    for (int j2 = 0; j2 < 4; ++j2)                                            \
      fb[j2] = *(const bf16x8*)&As[(wn + j2 * 16 + mrow) * 136 + k0];         \
    _Pragma("unroll")                                                         \
    for (int i2 = 0; i2 < 4; ++i2)                                            \
      _Pragma("unroll")                                                       \
      for (int j2 = 0; j2 < 4; ++j2)                                          \
        acc[i2][j2] =                                                         \
            __builtin_amdgcn_mfma_f32_16x16x32_bf16(fa[i2], fb[j2],           \
                                                    acc[i2][j2], 0, 0, 0);    \
  }

template <int LAYER>
__global__ __launch_bounds__(256, 2)
void biggemm_kernel(const u16* __restrict__ aggu, const u16* __restrict__ hbf,
                    const u16* __restrict__ Wt, const float* __restrict__ bias,
                    u16* __restrict__ hb_out, float* __restrict__ fout) {
  __shared__ u16 As[128 * 136]; // node-rows tile (agg_r or hbf), pad +8
  __shared__ u16 Ws[128 * 136]; // W rows = d
  int t = threadIdx.x;
  int n0 = blockIdx.x * 128;
  int wave = t >> 6, lane = t & 63;
  int wd = (wave & 1) * 64, wn = (wave >> 1) * 64;
  int mrow = lane & 15, quad = lane >> 4;
  float4 bv[4];
#pragma unroll
  for (int i = 0; i < 4; ++i) bv[i] = *(const float4*)&bias[wd + i * 16 + quad * 4];
  f32x4 acc[4][4];
#pragma unroll
  for (int i = 0; i < 4; ++i)
#pragma unroll
    for (int j = 0; j < 4; ++j) acc[i][j] = (f32x4){0.f, 0.f, 0.f, 0.f};

  uint4 ra0, ra1, ra2, ra3, ra4, ra5, ra6, ra7;
  uint4 rw0, rw1, rw2, rw3, rw4, rw5, rw6, rw7;
  const u16* srcbase = aggu;       // mat 0
  const u16* wbase = Wt;
  REP8(BG_ISSUE)
  for (int m = 0; m < 16; ++m) {
    REP8(BG_COMMIT)                 // vmcnt wait lands here, after a full MFMA phase
    __syncthreads();
    int mm = m + 1;
    srcbase = (mm < 16) ? aggu + (size_t)mm * NN * 128 : hbf;
    wbase = Wt + (size_t)mm * 16384;
    REP8(BG_ISSUE)                  // fire next mat's loads; no wait until next commit
    BG_MFMA
    __syncthreads();                // all waves done reading LDS before next commit
  }
  REP8(BG_COMMIT)                   // m = 16 (self loop), peeled
  __syncthreads();
  BG_MFMA

  // epilogue: lane owns node = n0+wn+j*16+mrow, d = wd+i*16+quad*4 .. +3 (contiguous)
#pragma unroll
  for (int j = 0; j < 4; ++j) {
    int n = n0 + wn + j * 16 + mrow;
    if (n < NN) {
#pragma unroll
      for (int i = 0; i < 4; ++i) {
        int d0 = wd + i * 16 + quad * 4;
        float v0 = acc[i][j][0] + bv[i].x;
        float v1 = acc[i][j][1] + bv[i].y;
        float v2 = acc[i][j][2] + bv[i].z;
        float v3 = acc[i][j][3] + bv[i].w;
        if (LAYER == 0) {
          v0 = fmaxf(v0, 0.f); v1 = fmaxf(v1, 0.f);
          v2 = fmaxf(v2, 0.f); v3 = fmaxf(v3, 0.f);
          uint2 st;
          st.x = pk2bf(v0, v1);
          st.y = pk2bf(v2, v3);
          *(uint2*)&hb_out[(size_t)n * 128 + d0] = st;
        } else {
          float4 st = make_float4(v0, v1, v2, v3);
          *(float4*)&fout[(size_t)n * 128 + d0] = st;
        }
      }
    }
  }
}

// ---------------- host ----------------
extern "C" void kernel_launch(void* const* d_in, const int* in_sizes, int n_in,
                              void* d_out, int out_size, void* d_ws, size_t ws_size,
                              hipStream_t stream) {
  const float* h0   = (const float*)d_in[0];
  const float* norm = (const float*)d_in[1];
  const float* w0   = (const float*)d_in[2];
  const float* b0   = (const float*)d_in[3];
  const float* lw0  = (const float*)d_in[4];
  const float* gw0  = (const float*)d_in[5];
  const float* w1   = (const float*)d_in[6];
  const float* b1   = (const float*)d_in[7];
  const float* lw1  = (const float*)d_in[8];
  const float* gw1  = (const float*)d_in[9];
  const int*   src  = (const int*)d_in[10];
  const int*   dst  = (const int*)d_in[11];
  const int*   rel  = (const int*)d_in[12];
  float* out = (float*)d_out;

  char* p = (char*)d_ws;
  auto alloc = [&](size_t bytes) -> void* {
    void* q = (void*)p;
    p += (bytes + 255) & ~(size_t)255;
    return q;
  };
  u16*   Wt     = (u16*)alloc((size_t)34 * 16384 * 2);
  float* gates  = (float*)alloc((size_t)NR * NN * 4);
  u16*   hbf0   = (u16*)alloc((size_t)NN * 128 * 2);
  u16*   hbf1   = (u16*)alloc((size_t)NN * 128 * 2);
  int*   counts = (int*)alloc((size_t)NP * 4);
  int*   cursor = (int*)alloc((size_t)NP * 4);
  int*   starts = (int*)alloc((size_t)(NP + 1) * 4);
  int*   bsum   = (int*)alloc((size_t)NB1 * 4);
  int*   boff   = (int*)alloc((size_t)NB1 * 4);
  uint2* esd    = (uint2*)alloc((size_t)NE * 8);
  u32*   agg    = (u32*)alloc((size_t)NN * NR * 64 * 4); // [r][v][128] bf16 = 204.8 MB

  // ---- sort edges by (dst, rel) — shared by both layers ----
  hipMemsetAsync(counts, 0, (size_t)NP * 4, stream);
  hist_kernel<<<NE / 256, 256, 0, stream>>>(dst, rel, counts);
  scan_partial<<<NB1, 256, 0, stream>>>(counts, bsum);
  scan_mid<<<1, 1024, 0, stream>>>(bsum, boff, starts + NP);
  scan_final<<<NB1, 256, 0, stream>>>(counts, boff, starts, cursor);
  scatter_kernel<<<NE / 256, 256, 0, stream>>>(src, dst, rel, norm, cursor, esd);
  convert_wt<<<dim3(64, 34), 256, 0, stream>>>(w0, lw0, w1, lw1, Wt);
  hconv_kernel<<<NN * 32 / 256, 256, 0, stream>>>(h0, hbf0);

  // ---- layer 0 (relu, bf16 output) ----
  gates_kernel<<<NN / 16, 256, 0, stream>>>(hbf0, gw0, gates);
  aggregate_kernel<<<(NN + 3) / 4, 256, 0, stream>>>(
      (const u32*)hbf0, esd, gates, starts, agg);
  biggemm_kernel<0><<<NTILES, 256, 0, stream>>>(
      (const u16*)agg, hbf0, Wt, b0, hbf1, nullptr);

  // ---- layer 1 (no relu, f32 output) ----
  gates_kernel<<<NN / 16, 256, 0, stream>>>(hbf1, gw1, gates);
  aggregate_kernel<<<(NN + 3) / 4, 256, 0, stream>>>(
      (const u32*)hbf1, esd, gates, starts, agg);
  biggemm_kernel<1><<<NTILES, 256, 0, stream>>>(
      (const u16*)agg, hbf1, Wt + (size_t)17 * 16384, b1, nullptr, out);
}